// Round 1
// baseline (379.722 us; speedup 1.0000x reference)
//
#include <hip/hip_runtime.h>

#define NN 50000
#define NE 800000
#define FIN 256
#define FH 64
#define FL 32

// ---------------- degree / dinv ----------------
__global__ __launch_bounds__(256) void k_deg_init(float* __restrict__ deg) {
    int i = blockIdx.x * 256 + threadIdx.x;
    if (i < NN) deg[i] = 1.0f;  // self-loop
}

__global__ __launch_bounds__(256) void k_deg_count(const int* __restrict__ dst,
                                                   float* __restrict__ deg) {
    int e = blockIdx.x * 256 + threadIdx.x;
    if (e < NE) atomicAdd(&deg[dst[e]], 1.0f);
}

__global__ __launch_bounds__(256) void k_dinv(float* __restrict__ deg) {
    int i = blockIdx.x * 256 + threadIdx.x;
    if (i < NN) deg[i] = rsqrtf(deg[i]);
}

// ---------------- GEMM1: h1 = x @ W1  [NN,256]x[256,64] ----------------
// block 256 threads, 16 nodes/block (NN/16 = 3125 exact). Wave w handles
// nodes 4w..4w+3; lane f in 0..63 computes feature f for those 4 nodes.
__global__ __launch_bounds__(256) void k_gemm1(const float* __restrict__ x,
                                               const float* __restrict__ W1,
                                               float* __restrict__ h1) {
    __shared__ float xs[16][FIN];  // 16 KB
    int nb = blockIdx.x * 16;
    const float4* xv = (const float4*)(x + (size_t)nb * FIN);
    float4* xsv = (float4*)&xs[0][0];
    for (int idx = threadIdx.x; idx < 16 * (FIN / 4); idx += 256)
        xsv[idx] = xv[idx];
    __syncthreads();

    int f = threadIdx.x & 63;
    int g = threadIdx.x >> 6;  // 0..3
    float a0 = 0.f, a1 = 0.f, a2 = 0.f, a3 = 0.f;
    #pragma unroll 4
    for (int k = 0; k < FIN; ++k) {
        float w = W1[k * FH + f];
        a0 += w * xs[g * 4 + 0][k];
        a1 += w * xs[g * 4 + 1][k];
        a2 += w * xs[g * 4 + 2][k];
        a3 += w * xs[g * 4 + 3][k];
    }
    int n0 = nb + g * 4;
    h1[(size_t)(n0 + 0) * FH + f] = a0;
    h1[(size_t)(n0 + 1) * FH + f] = a1;
    h1[(size_t)(n0 + 2) * FH + f] = a2;
    h1[(size_t)(n0 + 3) * FH + f] = a3;
}

// ---------------- init1: h2 = h1*dinv^2 + b1 (self-loop + bias) ----------------
__global__ __launch_bounds__(256) void k_init1(const float* __restrict__ h1,
                                               const float* __restrict__ dinv,
                                               const float* __restrict__ b1,
                                               float* __restrict__ h2) {
    int t = blockIdx.x * 256 + threadIdx.x;  // NN*FH threads, exact
    int n = t >> 6, f = t & 63;
    float di = dinv[n];
    h2[t] = h1[t] * di * di + b1[f];
}

// ---------------- scatter1: h2[dst] += h1[src]*dinv[src]*dinv[dst] ----------------
__global__ __launch_bounds__(256) void k_scatter1(const int* __restrict__ src,
                                                  const int* __restrict__ dst,
                                                  const float* __restrict__ h1,
                                                  const float* __restrict__ dinv,
                                                  float* __restrict__ h2) {
    long long t = (long long)blockIdx.x * 256 + threadIdx.x;  // NE*FH threads, exact
    int e = (int)(t >> 6), f = (int)(t & 63);
    int s = src[e], d = dst[e];
    float nrm = dinv[s] * dinv[d];
    atomicAdd(&h2[(size_t)d * FH + f], h1[(size_t)s * FH + f] * nrm);
}

// ---------------- GEMM2: h3 = relu(h2) @ W2  [NN,64]x[64,32] ----------------
// block 256 threads, 32 nodes/block. Lane f in 0..31 computes feature f for 4 nodes.
__global__ __launch_bounds__(256) void k_gemm2(const float* __restrict__ h2,
                                               const float* __restrict__ W2,
                                               float* __restrict__ h3) {
    __shared__ float xs[32][FH];  // 8 KB
    int nb = blockIdx.x * 32;
    int nrows = min(32, NN - nb);
    const float4* xv = (const float4*)(h2 + (size_t)nb * FH);
    float4* xsv = (float4*)&xs[0][0];
    for (int idx = threadIdx.x; idx < nrows * (FH / 4); idx += 256) {
        float4 v = xv[idx];
        v.x = fmaxf(v.x, 0.f); v.y = fmaxf(v.y, 0.f);
        v.z = fmaxf(v.z, 0.f); v.w = fmaxf(v.w, 0.f);
        xsv[idx] = v;
    }
    __syncthreads();

    int f = threadIdx.x & 31;
    int g = threadIdx.x >> 5;  // 0..7
    float a0 = 0.f, a1 = 0.f, a2 = 0.f, a3 = 0.f;
    #pragma unroll 4
    for (int k = 0; k < FH; ++k) {
        float w = W2[k * FL + f];
        a0 += w * xs[g * 4 + 0][k];
        a1 += w * xs[g * 4 + 1][k];
        a2 += w * xs[g * 4 + 2][k];
        a3 += w * xs[g * 4 + 3][k];
    }
    int n0 = nb + g * 4;
    if (n0 + 0 < NN) h3[(size_t)(n0 + 0) * FL + f] = a0;
    if (n0 + 1 < NN) h3[(size_t)(n0 + 1) * FL + f] = a1;
    if (n0 + 2 < NN) h3[(size_t)(n0 + 2) * FL + f] = a2;
    if (n0 + 3 < NN) h3[(size_t)(n0 + 3) * FL + f] = a3;
}

// ---------------- init2: out = h3*dinv^2 + b2 ----------------
__global__ __launch_bounds__(256) void k_init2(const float* __restrict__ h3,
                                               const float* __restrict__ dinv,
                                               const float* __restrict__ b2,
                                               float* __restrict__ out) {
    int t = blockIdx.x * 256 + threadIdx.x;  // NN*FL threads, exact
    int n = t >> 5, f = t & 31;
    float di = dinv[n];
    out[t] = h3[t] * di * di + b2[f];
}

// ---------------- scatter2: out[dst] += h3[src]*norm ----------------
__global__ __launch_bounds__(256) void k_scatter2(const int* __restrict__ src,
                                                  const int* __restrict__ dst,
                                                  const float* __restrict__ h3,
                                                  const float* __restrict__ dinv,
                                                  float* __restrict__ out) {
    long long t = (long long)blockIdx.x * 256 + threadIdx.x;  // NE*FL threads, exact
    int e = (int)(t >> 5), f = (int)(t & 31);
    int s = src[e], d = dst[e];
    float nrm = dinv[s] * dinv[d];
    atomicAdd(&out[(size_t)d * FL + f], h3[(size_t)s * FL + f] * nrm);
}

extern "C" void kernel_launch(void* const* d_in, const int* in_sizes, int n_in,
                              void* d_out, int out_size, void* d_ws, size_t ws_size,
                              hipStream_t stream) {
    const float* x  = (const float*)d_in[0];
    const int*   ei = (const int*)d_in[1];   // [2, NE] int32
    const float* W1 = (const float*)d_in[2];
    const float* b1 = (const float*)d_in[3];
    const float* W2 = (const float*)d_in[4];
    const float* b2 = (const float*)d_in[5];
    float* out = (float*)d_out;

    const int* src = ei;
    const int* dst = ei + NE;

    char* ws = (char*)d_ws;
    float* deg = (float*)(ws);                       // 200 KB used
    float* h1  = (float*)(ws + (size_t)1  * (1u << 20));  // 12.8 MB
    float* h2  = (float*)(ws + (size_t)14 * (1u << 20));  // 12.8 MB
    float* h3  = (float*)(ws + (size_t)27 * (1u << 20));  // 6.4 MB

    hipLaunchKernelGGL(k_deg_init, dim3((NN + 255) / 256), dim3(256), 0, stream, deg);
    hipLaunchKernelGGL(k_deg_count, dim3((NE + 255) / 256), dim3(256), 0, stream, dst, deg);
    hipLaunchKernelGGL(k_dinv, dim3((NN + 255) / 256), dim3(256), 0, stream, deg);

    hipLaunchKernelGGL(k_gemm1, dim3(NN / 16), dim3(256), 0, stream, x, W1, h1);
    hipLaunchKernelGGL(k_init1, dim3(NN * FH / 256), dim3(256), 0, stream, h1, deg, b1, h2);
    hipLaunchKernelGGL(k_scatter1, dim3(NE * FH / 256), dim3(256), 0, stream, src, dst, h1, deg, h2);

    hipLaunchKernelGGL(k_gemm2, dim3((NN + 31) / 32), dim3(256), 0, stream, h2, W2, h3);
    hipLaunchKernelGGL(k_init2, dim3(NN * FL / 256), dim3(256), 0, stream, h3, deg, b2, out);
    hipLaunchKernelGGL(k_scatter2, dim3(NE * FL / 256), dim3(256), 0, stream, src, dst, h3, deg, out);
}

// Round 2
// 238.150 us; speedup vs baseline: 1.5945x; 1.5945x over previous
//
#include <hip/hip_runtime.h>

#define NN 50000
#define NE 800000
#define FIN 256
#define FH 64
#define FL 32

#define SCAN_B 256
#define NBLK ((NN + SCAN_B - 1) / SCAN_B)   // 196

// ---------------- small utility kernels ----------------
__global__ __launch_bounds__(256) void k_zero_int(int* __restrict__ p, int n) {
    int i = blockIdx.x * 256 + threadIdx.x;
    if (i < n) p[i] = 0;
}

// int histogram of dst (in-degree, no self-loop)
__global__ __launch_bounds__(256) void k_hist(const int* __restrict__ dst,
                                              int* __restrict__ ideg) {
    int e = blockIdx.x * 256 + threadIdx.x;
    if (e < NE) atomicAdd(&ideg[dst[e]], 1);
}

// dinv = rsqrt(ideg + 1)   (self-loop included in degree)
__global__ __launch_bounds__(256) void k_dinv(const int* __restrict__ ideg,
                                              float* __restrict__ dinv) {
    int i = blockIdx.x * 256 + threadIdx.x;
    if (i < NN) dinv[i] = rsqrtf((float)(ideg[i] + 1));
}

// ---------------- hierarchical exclusive scan over ideg ----------------
__global__ __launch_bounds__(SCAN_B) void k_scan1(const int* __restrict__ ideg,
                                                  int* __restrict__ row_start,
                                                  int* __restrict__ partials) {
    __shared__ int tmp[SCAN_B];
    int tid = threadIdx.x;
    int i = blockIdx.x * SCAN_B + tid;
    int v = (i < NN) ? ideg[i] : 0;
    tmp[tid] = v;
    __syncthreads();
    for (int off = 1; off < SCAN_B; off <<= 1) {
        int t = (tid >= off) ? tmp[tid - off] : 0;
        __syncthreads();
        tmp[tid] += t;
        __syncthreads();
    }
    if (i < NN) row_start[i] = tmp[tid] - v;          // exclusive
    if (tid == SCAN_B - 1) partials[blockIdx.x] = tmp[tid];
}

__global__ __launch_bounds__(SCAN_B) void k_scan2(int* __restrict__ partials) {
    __shared__ int tmp[SCAN_B];
    int tid = threadIdx.x;
    int v = (tid < NBLK) ? partials[tid] : 0;
    tmp[tid] = v;
    __syncthreads();
    for (int off = 1; off < SCAN_B; off <<= 1) {
        int t = (tid >= off) ? tmp[tid - off] : 0;
        __syncthreads();
        tmp[tid] += t;
        __syncthreads();
    }
    if (tid < NBLK) partials[tid] = tmp[tid] - v;     // exclusive
}

__global__ __launch_bounds__(SCAN_B) void k_scan3(int* __restrict__ row_start,
                                                  const int* __restrict__ partials,
                                                  int* __restrict__ cursor) {
    int i = blockIdx.x * SCAN_B + threadIdx.x;
    if (i < NN) {
        int r = row_start[i] + partials[blockIdx.x];
        row_start[i] = r;
        cursor[i] = r;
    }
}

// fill CSR: csr_src[pos] = src[e], bucketed by dst
__global__ __launch_bounds__(256) void k_fill(const int* __restrict__ src,
                                              const int* __restrict__ dst,
                                              int* __restrict__ cursor,
                                              int* __restrict__ csr_src) {
    int e = blockIdx.x * 256 + threadIdx.x;
    if (e < NE) {
        int pos = atomicAdd(&cursor[dst[e]], 1);
        csr_src[pos] = src[e];
    }
}

// ---------------- GEMM1: h1 = x @ W1  [NN,256]x[256,64] ----------------
__global__ __launch_bounds__(256) void k_gemm1(const float* __restrict__ x,
                                               const float* __restrict__ W1,
                                               float* __restrict__ h1) {
    __shared__ float xs[16][FIN];  // 16 KB
    int nb = blockIdx.x * 16;
    const float4* xv = (const float4*)(x + (size_t)nb * FIN);
    float4* xsv = (float4*)&xs[0][0];
    for (int idx = threadIdx.x; idx < 16 * (FIN / 4); idx += 256)
        xsv[idx] = xv[idx];
    __syncthreads();

    int f = threadIdx.x & 63;
    int g = threadIdx.x >> 6;  // 0..3
    float a0 = 0.f, a1 = 0.f, a2 = 0.f, a3 = 0.f;
    #pragma unroll 4
    for (int k = 0; k < FIN; ++k) {
        float w = W1[k * FH + f];
        a0 += w * xs[g * 4 + 0][k];
        a1 += w * xs[g * 4 + 1][k];
        a2 += w * xs[g * 4 + 2][k];
        a3 += w * xs[g * 4 + 3][k];
    }
    int n0 = nb + g * 4;
    h1[(size_t)(n0 + 0) * FH + f] = a0;
    h1[(size_t)(n0 + 1) * FH + f] = a1;
    h1[(size_t)(n0 + 2) * FH + f] = a2;
    h1[(size_t)(n0 + 3) * FH + f] = a3;
}

// ---------------- gather1: h2 = relu(dinv[d]*(Σ dinv[s] h1[s] + dinv[d] h1[d]) + b1) ----------------
// 4 nodes per 256-thread block; 64 lanes (features) per node.
__global__ __launch_bounds__(256) void k_gather1(const float* __restrict__ h1,
                                                 const float* __restrict__ dinv,
                                                 const int* __restrict__ row_start,
                                                 const int* __restrict__ ideg,
                                                 const int* __restrict__ csr_src,
                                                 const float* __restrict__ b1,
                                                 float* __restrict__ h2) {
    int d = blockIdx.x * 4 + (threadIdx.x >> 6);
    int f = threadIdx.x & 63;
    if (d >= NN) return;
    int row = row_start[d];
    int cnt = ideg[d];
    float dd = dinv[d];
    float acc = h1[(size_t)d * FH + f] * dd;   // self-loop term
    int j = 0;
    for (; j + 2 <= cnt; j += 2) {
        int s0 = csr_src[row + j];
        int s1 = csr_src[row + j + 1];
        float w0 = dinv[s0], w1 = dinv[s1];
        acc += h1[(size_t)s0 * FH + f] * w0;
        acc += h1[(size_t)s1 * FH + f] * w1;
    }
    if (j < cnt) {
        int s0 = csr_src[row + j];
        acc += h1[(size_t)s0 * FH + f] * dinv[s0];
    }
    h2[(size_t)d * FH + f] = fmaxf(acc * dd + b1[f], 0.f);
}

// ---------------- GEMM2: h3 = h2 @ W2  [NN,64]x[64,32]  (h2 already relu'd) ----------------
__global__ __launch_bounds__(256) void k_gemm2(const float* __restrict__ h2,
                                               const float* __restrict__ W2,
                                               float* __restrict__ h3) {
    __shared__ float xs[32][FH];  // 8 KB
    int nb = blockIdx.x * 32;
    int nrows = min(32, NN - nb);
    const float4* xv = (const float4*)(h2 + (size_t)nb * FH);
    float4* xsv = (float4*)&xs[0][0];
    for (int idx = threadIdx.x; idx < nrows * (FH / 4); idx += 256)
        xsv[idx] = xv[idx];
    __syncthreads();

    int f = threadIdx.x & 31;
    int g = threadIdx.x >> 5;  // 0..7
    float a0 = 0.f, a1 = 0.f, a2 = 0.f, a3 = 0.f;
    #pragma unroll 4
    for (int k = 0; k < FH; ++k) {
        float w = W2[k * FL + f];
        a0 += w * xs[g * 4 + 0][k];
        a1 += w * xs[g * 4 + 1][k];
        a2 += w * xs[g * 4 + 2][k];
        a3 += w * xs[g * 4 + 3][k];
    }
    int n0 = nb + g * 4;
    if (n0 + 0 < NN) h3[(size_t)(n0 + 0) * FL + f] = a0;
    if (n0 + 1 < NN) h3[(size_t)(n0 + 1) * FL + f] = a1;
    if (n0 + 2 < NN) h3[(size_t)(n0 + 2) * FL + f] = a2;
    if (n0 + 3 < NN) h3[(size_t)(n0 + 3) * FL + f] = a3;
}

// ---------------- gather2: out = dinv[d]*(Σ dinv[s] h3[s] + dinv[d] h3[d]) + b2 ----------------
// 8 nodes per 256-thread block; 32 lanes per node.
__global__ __launch_bounds__(256) void k_gather2(const float* __restrict__ h3,
                                                 const float* __restrict__ dinv,
                                                 const int* __restrict__ row_start,
                                                 const int* __restrict__ ideg,
                                                 const int* __restrict__ csr_src,
                                                 const float* __restrict__ b2,
                                                 float* __restrict__ out) {
    int d = blockIdx.x * 8 + (threadIdx.x >> 5);
    int f = threadIdx.x & 31;
    if (d >= NN) return;
    int row = row_start[d];
    int cnt = ideg[d];
    float dd = dinv[d];
    float acc = h3[(size_t)d * FL + f] * dd;
    int j = 0;
    for (; j + 2 <= cnt; j += 2) {
        int s0 = csr_src[row + j];
        int s1 = csr_src[row + j + 1];
        float w0 = dinv[s0], w1 = dinv[s1];
        acc += h3[(size_t)s0 * FL + f] * w0;
        acc += h3[(size_t)s1 * FL + f] * w1;
    }
    if (j < cnt) {
        int s0 = csr_src[row + j];
        acc += h3[(size_t)s0 * FL + f] * dinv[s0];
    }
    out[(size_t)d * FL + f] = acc * dd + b2[f];
}

extern "C" void kernel_launch(void* const* d_in, const int* in_sizes, int n_in,
                              void* d_out, int out_size, void* d_ws, size_t ws_size,
                              hipStream_t stream) {
    const float* x  = (const float*)d_in[0];
    const int*   ei = (const int*)d_in[1];   // [2, NE] int32
    const float* W1 = (const float*)d_in[2];
    const float* b1 = (const float*)d_in[3];
    const float* W2 = (const float*)d_in[4];
    const float* b2 = (const float*)d_in[5];
    float* out = (float*)d_out;

    const int* src = ei;
    const int* dst = ei + NE;

    // workspace layout (bytes):
    //   0.00 MB dinv      [NN f32]   200 KB
    //   0.25 MB ideg      [NN i32]   200 KB
    //   0.50 MB partials  [256 i32]  1 KB
    //   0.75 MB row_start [NN i32]   200 KB
    //   1.00 MB cursor    [NN i32]   200 KB
    //   1.25 MB csr_src   [NE i32]   3.2 MB
    //   4.50 MB h1        [NN*64 f32] 12.8 MB   (reused as h3 after gather1)
    //  17.50 MB h2        [NN*64 f32] 12.8 MB
    //  total ~30.3 MB
    char* ws = (char*)d_ws;
    float* dinv     = (float*)(ws);
    int*   ideg     = (int*)(ws + (size_t)(0.25 * (1 << 20)));
    int*   partials = (int*)(ws + (size_t)(0.50 * (1 << 20)));
    int*   row_start= (int*)(ws + (size_t)(0.75 * (1 << 20)));
    int*   cursor   = (int*)(ws + (size_t)(1.00 * (1 << 20)));
    int*   csr_src  = (int*)(ws + (size_t)(1.25 * (1 << 20)));
    float* h1       = (float*)(ws + (size_t)45 * (1u << 20) / 10);   // 4.5 MB
    float* h2       = (float*)(ws + (size_t)175 * (1u << 20) / 10);  // 17.5 MB
    float* h3       = h1;  // alias: h1 dead after gather1

    // --- CSR build ---
    hipLaunchKernelGGL(k_zero_int, dim3((NN + 255) / 256), dim3(256), 0, stream, ideg, NN);
    hipLaunchKernelGGL(k_hist, dim3((NE + 255) / 256), dim3(256), 0, stream, dst, ideg);
    hipLaunchKernelGGL(k_dinv, dim3((NN + 255) / 256), dim3(256), 0, stream, ideg, dinv);
    hipLaunchKernelGGL(k_scan1, dim3(NBLK), dim3(SCAN_B), 0, stream, ideg, row_start, partials);
    hipLaunchKernelGGL(k_scan2, dim3(1), dim3(SCAN_B), 0, stream, partials);
    hipLaunchKernelGGL(k_scan3, dim3(NBLK), dim3(SCAN_B), 0, stream, row_start, partials, cursor);
    hipLaunchKernelGGL(k_fill, dim3((NE + 255) / 256), dim3(256), 0, stream, src, dst, cursor, csr_src);

    // --- layer 1 ---
    hipLaunchKernelGGL(k_gemm1, dim3(NN / 16), dim3(256), 0, stream, x, W1, h1);
    hipLaunchKernelGGL(k_gather1, dim3((NN + 3) / 4), dim3(256), 0, stream,
                       h1, dinv, row_start, ideg, csr_src, b1, h2);

    // --- layer 2 ---
    hipLaunchKernelGGL(k_gemm2, dim3((NN + 31) / 32), dim3(256), 0, stream, h2, W2, h3);
    hipLaunchKernelGGL(k_gather2, dim3((NN + 7) / 8), dim3(256), 0, stream,
                       h3, dinv, row_start, ideg, csr_src, b2, out);
}